// Round 5
// baseline (31.843 us; speedup 1.0000x reference)
//
#include <hip/hip_runtime.h>
#include <math.h>

#define Bn   512
#define Tn   50
#define NAn  5
#define NCn  7
#define GHn  16
#define GWn  32
#define PC   (GHn*GWn)            // 512 cells per (batch,anchor) plane
#define NSLOT (Bn*NAn)            // 2560 partial slots
#define EXCL  0x8000

__device__ __constant__ float c_aw[NAn] = {1.0f, 2.0f, 3.5f, 5.0f, 8.0f};
__device__ __constant__ float c_ah[NAn] = {1.5f, 3.0f, 4.5f, 6.0f, 10.0f};

__device__ inline float sigm(float v) { return 1.0f / (1.0f + expf(-v)); }
__device__ inline float negterm(float v) {          // -log(clip(1-sigmoid(v)))
  return -logf(fmaxf(1.0f - sigm(v), 1e-12f));
}

__device__ inline float wred(float v) {
#pragma unroll
  for (int off = 32; off > 0; off >>= 1) v += __shfl_down(v, off, 64);
  return v;
}

// One block per (batch, anchor). blockIdx.x = anchor, blockIdx.y = batch.
// 128 threads. No global atomics; partials to private slot.
__global__ __launch_bounds__(128) void k_batch(const float* __restrict__ x,
                                               const float* __restrict__ tg,
                                               float* __restrict__ part)
{
  const int a   = blockIdx.x;
  const int b   = blockIdx.y;
  const int tid = threadIdx.x;

  __shared__ int   s_owner[PC];    // last-wins target tid per cell, -1 = none
  __shared__ int   s_flags[PC];    // bits0..6 label set; bit15 mask|ignore
  __shared__ float s_tx[Tn], s_ty[Tn], s_tw[Tn], s_th[Tn];

#pragma unroll
  for (int i = 0; i < PC / 128; ++i) { s_owner[tid + i * 128] = -1; s_flags[tid + i * 128] = 0; }
  __syncthreads();

  // ---- target phase: O(T), filtered to this anchor plane ----
  if (tid < Tn) {
    const float* tp = tg + ((size_t)b * Tn + tid) * 5;
    float c0 = tp[0], c1 = tp[1], c2 = tp[2], c3 = tp[3], c4 = tp[4];
    bool valid = (c0 + c1 + c2 + c3 + c4) > 0.0f;
    float gx = c1 * (float)GWn, gy = c2 * (float)GHn;
    float gw = c3 * (float)GWn, gh = c4 * (float)GHn;
    float iou[NAn];
    int best = 0; float bestv = -1.0f;
#pragma unroll
    for (int q = 0; q < NAn; ++q) {
      float inter = fminf(gw, c_aw[q]) * fminf(gh, c_ah[q]);
      float u = inter / (gw * gh + c_aw[q] * c_ah[q] - inter + 1e-16f);
      iou[q] = u;
      if (u > bestv) { bestv = u; best = q; }     // first-max like argmax
    }
    int gi = (int)floorf(gx), gj = (int)floorf(gy);
    bool inb = (gi >= 0) && (gi < GWn) && (gj >= 0) && (gj < GHn); // mode='drop'
    s_tx[tid] = gx - floorf(gx);
    s_ty[tid] = gy - floorf(gy);
    s_tw[tid] = logf(gw / c_aw[best] + 1e-16f);
    s_th[tid] = logf(gh / c_ah[best] + 1e-16f);
    if (valid && inb) {
      int cell = gj * GWn + gi;
      if (best == a) {
        atomicMax(&s_owner[cell], tid);           // last-wins = max tid
        int lbl = (int)c0;
        int lb  = (lbl >= 0 && lbl < NCn) ? (1 << lbl) : 0;  // mode='drop'
        atomicOr(&s_flags[cell], lb | EXCL);
      }
      if (iou[a] > 0.6f)
        atomicOr(&s_flags[cell], EXCL);
    }
  }
  __syncthreads();

  // ---- cell sweep: 4 cells/thread, one float4 conf load ----
  float v_mse = 0.f, v_pc = 0.f, v_cls = 0.f, v_neg = 0.f, v_np = 0.f, v_nc = 0.f;
  const float* pl = x + (size_t)(b * (NAn * 14) + a * 14) * PC;
  const int c0i = tid * 4;
  const float4 pv = *reinterpret_cast<const float4*>(pl + 6 * PC + c0i);
  const float p6v[4] = {pv.x, pv.y, pv.z, pv.w};

#pragma unroll
  for (int u = 0; u < 4; ++u) {
    int cell = c0i + u;
    int flags = s_flags[cell];
    float p6 = p6v[u];
    if (!(flags & EXCL)) {                        // negative cell
      v_neg += negterm(p6);
      v_nc  += 1.0f;
    }
    int owner = s_owner[cell];
    if (owner >= 0) {                             // positive (masked) cell
      float p0 = pl[0 * PC + cell];
      float p1 = pl[1 * PC + cell];
      float p2 = pl[2 * PC + cell];
      float p3 = pl[3 * PC + cell];
      float dx = sigm(p0) - s_tx[owner];
      float dy = sigm(p1) - s_ty[owner];
      float dw = p2 - s_tw[owner];
      float dh = p3 - s_th[owner];
      v_mse += dx * dx + dy * dy + dw * dw + dh * dh;
      v_pc  += -logf(fmaxf(sigm(p6), 1e-12f));
      v_np  += 1.0f;
      int bits = flags & 0x7F;
      if (bits) {
        float s[NCn]; float m = -1e30f;
#pragma unroll
        for (int k = 0; k < NCn; ++k) {
          s[k] = sigm(pl[(size_t)(7 + k) * PC + cell]);
          m = fmaxf(m, s[k]);
        }
        float ssum = 0.f;
#pragma unroll
        for (int k = 0; k < NCn; ++k) ssum += expf(s[k] - m);
        float lse = m + logf(ssum);
#pragma unroll
        for (int k = 0; k < NCn; ++k)
          if ((bits >> k) & 1) v_cls += lse - s[k];
      }
    }
  }

  // ---- block reduction (2 waves), plain store to private slot ----
  __shared__ float red6[2][6];
  float vals[6] = {v_mse, v_pc, v_cls, v_neg, v_np, v_nc};
  int wid = tid >> 6, lane = tid & 63;
#pragma unroll
  for (int k = 0; k < 6; ++k) {
    float r = wred(vals[k]);
    if (lane == 0) red6[wid][k] = r;
  }
  __syncthreads();
  if (tid < 6)
    part[(size_t)(b * NAn + a) * 8 + tid] = red6[0][tid] + red6[1][tid];
}

__global__ __launch_bounds__(256) void k_red(const float* __restrict__ part,
                                             float* __restrict__ out)
{
  const int tid = threadIdx.x;
  float v[6] = {0.f, 0.f, 0.f, 0.f, 0.f, 0.f};
#pragma unroll
  for (int r = 0; r < NSLOT / 256; ++r) {
    const float* p = part + (size_t)(tid + r * 256) * 8;
    float4 lo = *reinterpret_cast<const float4*>(p);
    float4 hi = *reinterpret_cast<const float4*>(p + 4);
    v[0] += lo.x; v[1] += lo.y; v[2] += lo.z; v[3] += lo.w;
    v[4] += hi.x; v[5] += hi.y;
  }
  __shared__ float red6[4][6];
  int wid = tid >> 6, lane = tid & 63;
#pragma unroll
  for (int k = 0; k < 6; ++k) {
    float r = wred(v[k]);
    if (lane == 0) red6[wid][k] = r;
  }
  __syncthreads();
  if (tid == 0) {
    float a0 = red6[0][0] + red6[1][0] + red6[2][0] + red6[3][0];
    float a1 = red6[0][1] + red6[1][1] + red6[2][1] + red6[3][1];
    float a2 = red6[0][2] + red6[1][2] + red6[2][2] + red6[3][2];
    float a3 = red6[0][3] + red6[1][3] + red6[2][3] + red6[3][3];
    float a4 = red6[0][4] + red6[1][4] + red6[2][4] + red6[3][4];
    float a5 = red6[0][5] + red6[1][5] + red6[2][5] + red6[3][5];
    float npos = fmaxf(a4, 1.0f);
    float negc = fmaxf(a5, 1.0f);
    out[0] = a0 / npos + a3 / negc + a1 / npos + a2 / ((float)Bn * npos);
  }
}

extern "C" void kernel_launch(void* const* d_in, const int* in_sizes, int n_in,
                              void* d_out, int out_size, void* d_ws, size_t ws_size,
                              hipStream_t stream)
{
  const float* x  = (const float*)d_in[0];
  const float* tg = (const float*)d_in[1];
  float* part = (float*)d_ws;                     // 2560*8 floats = 80 KB

  dim3 grid(NAn, Bn);
  k_batch<<<grid, 128, 0, stream>>>(x, tg, part);
  k_red<<<1, 256, 0, stream>>>(part, (float*)d_out);
}

// Round 6
// 27.998 us; speedup vs baseline: 1.1373x; 1.1373x over previous
//
#include <hip/hip_runtime.h>
#include <math.h>

#define Bn   512
#define Tn   50
#define NAn  5
#define NCn  7
#define GHn  16
#define GWn  32
#define PC   (GHn*GWn)            // 512 cells per anchor plane
#define CELLS (NAn*PC)            // 2560 cells per batch
#define EXCL  0x8000

__device__ __constant__ float c_aw[NAn] = {1.0f, 2.0f, 3.5f, 5.0f, 8.0f};
__device__ __constant__ float c_ah[NAn] = {1.5f, 3.0f, 4.5f, 6.0f, 10.0f};

__device__ inline float sigm(float v) { return 1.0f / (1.0f + expf(-v)); }
__device__ inline float negterm(float v) {          // -log(clip(1-sigmoid(v)))
  return -logf(fmaxf(1.0f - sigm(v), 1e-12f));
}

__device__ inline float wred(float v) {
#pragma unroll
  for (int off = 32; off > 0; off >>= 1) v += __shfl_down(v, off, 64);
  return v;
}

// One block per batch, 256 threads. All global loads issued at kernel top so
// HBM latency overlaps the target phase. No global atomics.
// Partials stored column-major: part[k*Bn + b].
__global__ __launch_bounds__(256) void k_batch(const float* __restrict__ x,
                                               const float* __restrict__ tg,
                                               float* __restrict__ part)
{
  const int b   = blockIdx.x;
  const int tid = threadIdx.x;

  // ---- issue conf loads FIRST (independent of LDS): 2 cells per anchor ----
  const float* xb = x + (size_t)b * (NAn * 14) * PC;
  float2 pc[NAn];
#pragma unroll
  for (int a = 0; a < NAn; ++a)
    pc[a] = *reinterpret_cast<const float2*>(xb + (a * 14 + 6) * PC + tid * 2);

  // ---- cooperative tg load into LDS (coalesced), also independent ----
  __shared__ float s_tg[Tn * 5];                  // 250 floats
  if (tid < Tn * 5) s_tg[tid] = tg[(size_t)b * (Tn * 5) + tid];

  __shared__ int   s_owner[CELLS];   // last-wins target tid per cell, -1 none
  __shared__ int   s_flags[CELLS];   // bits0..6 label set; bit15 mask|ignore
  __shared__ float s_tx[Tn], s_ty[Tn], s_tw[Tn], s_th[Tn];

#pragma unroll
  for (int i = 0; i < CELLS / 256; ++i) { s_owner[tid + i * 256] = -1; s_flags[tid + i * 256] = 0; }
  __syncthreads();

  // ---- target phase: O(T) owner-map build from LDS-resident targets ----
  if (tid < Tn) {
    float c0 = s_tg[tid * 5 + 0], c1 = s_tg[tid * 5 + 1], c2 = s_tg[tid * 5 + 2];
    float c3 = s_tg[tid * 5 + 3], c4 = s_tg[tid * 5 + 4];
    bool valid = (c0 + c1 + c2 + c3 + c4) > 0.0f;
    float gx = c1 * (float)GWn, gy = c2 * (float)GHn;
    float gw = c3 * (float)GWn, gh = c4 * (float)GHn;
    float iou[NAn];
    int best = 0; float bestv = -1.0f;
#pragma unroll
    for (int q = 0; q < NAn; ++q) {
      float inter = fminf(gw, c_aw[q]) * fminf(gh, c_ah[q]);
      float u = inter / (gw * gh + c_aw[q] * c_ah[q] - inter + 1e-16f);
      iou[q] = u;
      if (u > bestv) { bestv = u; best = q; }     // first-max like argmax
    }
    int gi = (int)floorf(gx), gj = (int)floorf(gy);
    bool inb = (gi >= 0) && (gi < GWn) && (gj >= 0) && (gj < GHn); // mode='drop'
    s_tx[tid] = gx - floorf(gx);
    s_ty[tid] = gy - floorf(gy);
    s_tw[tid] = logf(gw / c_aw[best] + 1e-16f);
    s_th[tid] = logf(gh / c_ah[best] + 1e-16f);
    if (valid && inb) {
      int pcell = gj * GWn + gi;
      int cell  = best * PC + pcell;
      atomicMax(&s_owner[cell], tid);             // last-wins = max tid
      int lbl = (int)c0;
      int lb  = (lbl >= 0 && lbl < NCn) ? (1 << lbl) : 0;  // mode='drop'
      atomicOr(&s_flags[cell], lb | EXCL);
#pragma unroll
      for (int q = 0; q < NAn; ++q) if (iou[q] > 0.6f)
        atomicOr(&s_flags[q * PC + pcell], EXCL);
    }
  }
  __syncthreads();

  // ---- sweep: conf already in registers; 2 cells per anchor per thread ----
  float v_mse = 0.f, v_pc = 0.f, v_cls = 0.f, v_neg = 0.f, v_np = 0.f, v_nc = 0.f;
#pragma unroll
  for (int a = 0; a < NAn; ++a) {
    const float p6v[2] = {pc[a].x, pc[a].y};
    const float* pl = xb + a * 14 * PC;
#pragma unroll
    for (int u = 0; u < 2; ++u) {
      int pcell = tid * 2 + u;
      int cell  = a * PC + pcell;
      int flags = s_flags[cell];
      float p6  = p6v[u];
      if (!(flags & EXCL)) {                      // negative cell
        v_neg += negterm(p6);
        v_nc  += 1.0f;
      }
      int owner = s_owner[cell];
      if (owner >= 0) {                           // positive (masked) cell
        float p0 = pl[0 * PC + pcell];
        float p1 = pl[1 * PC + pcell];
        float p2 = pl[2 * PC + pcell];
        float p3 = pl[3 * PC + pcell];
        float dx = sigm(p0) - s_tx[owner];
        float dy = sigm(p1) - s_ty[owner];
        float dw = p2 - s_tw[owner];
        float dh = p3 - s_th[owner];
        v_mse += dx * dx + dy * dy + dw * dw + dh * dh;
        v_pc  += -logf(fmaxf(sigm(p6), 1e-12f));
        v_np  += 1.0f;
        int bits = flags & 0x7F;
        if (bits) {
          float s[NCn]; float m = -1e30f;
#pragma unroll
          for (int k = 0; k < NCn; ++k) {
            s[k] = sigm(pl[(size_t)(7 + k) * PC + pcell]);
            m = fmaxf(m, s[k]);
          }
          float ssum = 0.f;
#pragma unroll
          for (int k = 0; k < NCn; ++k) ssum += expf(s[k] - m);
          float lse = m + logf(ssum);
#pragma unroll
          for (int k = 0; k < NCn; ++k)
            if ((bits >> k) & 1) v_cls += lse - s[k];
        }
      }
    }
  }

  // ---- block reduction, plain column-major store ----
  __shared__ float red6[4][6];
  float vals[6] = {v_mse, v_pc, v_cls, v_neg, v_np, v_nc};
  int wid = tid >> 6, lane = tid & 63;
#pragma unroll
  for (int k = 0; k < 6; ++k) {
    float r = wred(vals[k]);
    if (lane == 0) red6[wid][k] = r;
  }
  __syncthreads();
  if (tid < 6)
    part[(size_t)tid * Bn + b] = red6[0][tid] + red6[1][tid] + red6[2][tid] + red6[3][tid];
}

__global__ __launch_bounds__(256) void k_red(const float* __restrict__ part,
                                             float* __restrict__ out)
{
  const int tid = threadIdx.x;
  float v[6];
#pragma unroll
  for (int k = 0; k < 6; ++k)                      // coalesced column reads
    v[k] = part[(size_t)k * Bn + tid] + part[(size_t)k * Bn + tid + 256];

  __shared__ float red6[4][6];
  int wid = tid >> 6, lane = tid & 63;
#pragma unroll
  for (int k = 0; k < 6; ++k) {
    float r = wred(v[k]);
    if (lane == 0) red6[wid][k] = r;
  }
  __syncthreads();
  if (tid == 0) {
    float a0 = red6[0][0] + red6[1][0] + red6[2][0] + red6[3][0];
    float a1 = red6[0][1] + red6[1][1] + red6[2][1] + red6[3][1];
    float a2 = red6[0][2] + red6[1][2] + red6[2][2] + red6[3][2];
    float a3 = red6[0][3] + red6[1][3] + red6[2][3] + red6[3][3];
    float a4 = red6[0][4] + red6[1][4] + red6[2][4] + red6[3][4];
    float a5 = red6[0][5] + red6[1][5] + red6[2][5] + red6[3][5];
    float npos = fmaxf(a4, 1.0f);
    float negc = fmaxf(a5, 1.0f);
    out[0] = a0 / npos + a3 / negc + a1 / npos + a2 / ((float)Bn * npos);
  }
}

extern "C" void kernel_launch(void* const* d_in, const int* in_sizes, int n_in,
                              void* d_out, int out_size, void* d_ws, size_t ws_size,
                              hipStream_t stream)
{
  const float* x  = (const float*)d_in[0];
  const float* tg = (const float*)d_in[1];
  float* part = (float*)d_ws;                     // 6*512 floats = 12 KB

  k_batch<<<Bn, 256, 0, stream>>>(x, tg, part);
  k_red<<<1, 256, 0, stream>>>(part, (float*)d_out);
}